// Round 12
// baseline (243.076 us; speedup 1.0000x reference)
//
#include <hip/hip_runtime.h>
#include <stdint.h>
#include <math.h>

// Problem constants
constexpr int T_ = 4;
constexpr int B_ = 8;
constexpr int C_ = 256;
constexpr int N_ = 256;          // H*W
constexpr int TN_ = 1024;        // T*N
constexpr int NH_ = 8;           // heads
constexpr int O3_ = 768;         // 3*C
constexpr int BIAS_ROWS_ = 6727; // 7*31*31

__device__ __constant__ int TI_OF[10] = {0,1,1,2,2,2,3,3,3,3};
__device__ __constant__ int TJ_OF[10] = {0,0,1,0,1,2,0,1,2,3};

__device__ __forceinline__ float quant1f(float m) {
    return rintf(fminf(fmaxf(m, 0.0f), 1.0f));
}

// ---------------------------------------------------------------------------
// K1 (v8): 8x8 microtile, LDS-read-count cut 1.5x vs v6.
// Model: v6 is LDS-ISSUE-bound: 2.36M ds_read_b128 x 12cyc / 256CU = 46us
// (matches 49.5 measured; VALU floor is 20.5). 8x8 -> 4 reads/64 FMA ->
// 1.57M reads -> floor 30.7us. v2's 8x8 failed on 4-way bank conflicts;
// v8 uses group-pitch-12 (8-float groups at 12-float pitch): read banks
// g*12%32 = {0,12,24,4,16,28,8,20} all distinct, 16B-aligned -> all reads
// conflict-free. Tile 128(o) x 64 cols(16n x 4t), 128 thr, grid (16,6,8)
// = 768 blocks = 3/CU = 6 waves/CU (LDS pipe is per-CU -> sufficient).
// kc/cc/FMA order per output unchanged -> bit-identical.
// ---------------------------------------------------------------------------
__global__ __launch_bounds__(128) void k1_qkv_lif(
    const float* __restrict__ x, const float* __restrict__ w,
    const float* __restrict__ gamma, const float* __restrict__ beta,
    const float* __restrict__ mean, const float* __restrict__ var,
    uint32_t* __restrict__ qb, uint32_t* __restrict__ kb, uint32_t* __restrict__ vb)
{
    __shared__ float At[32][192];  // [k][row'], row' = (row>>3)*12 + (row&7)
    __shared__ float Bt[32][96];   // [k][col'], col' = (nl>>1)*12 + (nl&1)*4 + t
    const int b = blockIdx.z;
    const int oBase = blockIdx.y * 128;
    const int nBase = blockIdx.x * 16;
    const int tid = threadIdx.x;   // 0..127
    const float* xb = x + (size_t)b * C_ * TN_;

    // compute mapping: 16 row-groups x 8 = 128 (tyc); 8 col-groups x 8 = 64 (txc)
    const int tyc = tid >> 3;      // 0..15
    const int txc = tid & 7;       // 0..7  (cols txc*8..+7 = 2 n x 4 t)

    // A loader: row = oBase + tid (one row/thread), 8 x float4 over k
    const int a_rowp = (tid >> 3) * 12 + (tid & 7);   // padded row index
    // B loader: 4 (kk, n_loc) pairs per thread
    const int b_kk0 = tid >> 4;    // 0..7
    const int b_nl = tid & 15;     // 0..15
    const int b_colp = (b_nl >> 1) * 12 + (b_nl & 1) * 4;  // 16B-aligned

    float acc[8][8];               // [o-local][jn*4 + t]
#pragma unroll
    for (int i = 0; i < 8; ++i)
#pragma unroll
        for (int j = 0; j < 8; ++j) acc[i][j] = 0.0f;

    for (int kc = 0; kc < 8; ++kc) {
        const int k0 = kc * 32;
        // A staging: w[oBase+tid][k0..k0+31] -> At[k][row'] (scatter, 2-way free)
#pragma unroll
        for (int u = 0; u < 8; ++u) {
            const float4 v = *(const float4*)&w[(size_t)(oBase + tid) * C_ + k0 + 4 * u];
            At[4 * u + 0][a_rowp] = v.x;
            At[4 * u + 1][a_rowp] = v.y;
            At[4 * u + 2][a_rowp] = v.z;
            At[4 * u + 3][a_rowp] = v.w;
        }
        // B staging: t-transpose in regs, one aligned b128 per (kk, n_loc)
#pragma unroll
        for (int r = 0; r < 4; ++r) {
            const int kk = b_kk0 + 8 * r;
            const float* src = &xb[(size_t)(k0 + kk) * TN_ + nBase + b_nl];
            float4 v;
            v.x = src[0];     // t = 0
            v.y = src[256];   // t = 1
            v.z = src[512];   // t = 2
            v.w = src[768];   // t = 3
            *(float4*)&Bt[kk][b_colp] = v;
        }
        __syncthreads();
#pragma unroll
        for (int cc = 0; cc < 32; ++cc) {
            float a[8], bb[8];
            *(float4*)&a[0] = *(const float4*)&At[cc][tyc * 12];
            *(float4*)&a[4] = *(const float4*)&At[cc][tyc * 12 + 4];
            *(float4*)&bb[0] = *(const float4*)&Bt[cc][txc * 12];
            *(float4*)&bb[4] = *(const float4*)&Bt[cc][txc * 12 + 4];
#pragma unroll
            for (int i = 0; i < 8; ++i)
#pragma unroll
                for (int j = 0; j < 8; ++j) acc[i][j] += a[i] * bb[j];
        }
        __syncthreads();
    }

    // epilogue: BN + LIF over t + bit-pack, for 8 o's x 2 n's (bit-identical)
    const int o0 = oBase + tyc * 8;
    const int which = o0 >> 8;          // 0=q 1=k 2=v (thread-uniform)
    const int h = (o0 >> 5) & 7;
    const int dq = (o0 >> 3) & 3;       // byte-quarter within the 32-d word
    const int n0 = nBase + txc * 2;
    uint8_t* dst = (uint8_t*)((which == 0) ? qb : (which == 1) ? kb : vb);

#pragma unroll
    for (int jn = 0; jn < 2; ++jn) {
        uint32_t bits[4] = {0u, 0u, 0u, 0u};
#pragma unroll
        for (int i = 0; i < 8; ++i) {
            const int o = o0 + i;
            const float inv = 1.0f / sqrtf(var[o] + 1e-5f);
            const float g = gamma[o] * inv;
            const float mn = mean[o], bt = beta[o];
            float memv = 0.0f, spk = 0.0f;
#pragma unroll
            for (int t = 0; t < 4; ++t) {
                const float val = (acc[i][jn * 4 + t] - mn) * g + bt;
                const float m = (memv - 0.5f * spk) * 0.25f + val;
                memv = m;
                const float s = quant1f(m);
                spk = s;
                bits[t] |= ((uint32_t)s) << i;
            }
        }
#pragma unroll
        for (int t = 0; t < 4; ++t)
            dst[4 * (((size_t)b * NH_ + h) * TN_ + t * N_ + n0 + jn) + dq] = (uint8_t)bits[t];
    }
}

// ---------------------------------------------------------------------------
// K3gram (v2): fused tgp + cum, quarter-split. Grid (64,4) = 256 blocks.
// Integer popcount math -> exact.
// ---------------------------------------------------------------------------
__global__ __launch_bounds__(256) void k3_gram(
    const uint32_t* __restrict__ kb, const uint32_t* __restrict__ vb,
    float* __restrict__ Gf)
{
    __shared__ uint64_t ks8[8][4];
    __shared__ uint64_t vs[32][4];
    const int bh = blockIdx.x;
    const int qd = blockIdx.y;          // d2-quarter 0..3
    const int tid = threadIdx.x;
    const int q = tid >> 6, lane = tid & 63;
    const int d = tid & 31;
    const int d2l = tid >> 5;           // 0..7 (local d2)

    int cum = 0;

    for (int t = 0; t < T_; ++t) {
        const int j = t * N_ + tid;
        const uint32_t kw = kb[(size_t)bh * TN_ + j];
        const uint32_t vw = vb[(size_t)bh * TN_ + j];
#pragma unroll
        for (int dd = 0; dd < 8; ++dd) {
            const uint64_t mk = __ballot((kw >> (8 * qd + dd)) & 1u);
            if (lane == 0) ks8[dd][q] = mk;
        }
#pragma unroll
        for (int dd = 0; dd < 32; ++dd) {
            const uint64_t mv = __ballot((vw >> dd) & 1u);
            if (lane == 0) vs[dd][q] = mv;
        }
        __syncthreads();
        int p = 0;
#pragma unroll
        for (int w = 0; w < 4; ++w) p += __popcll(ks8[d2l][w] & vs[d][w]);
        cum += p;
        Gf[(size_t)(bh * 4 + t) * 1024 + 256 * qd + tid] = (float)cum;
        __syncthreads();   // ks8/vs reused next t
    }
}

// ---------------------------------------------------------------------------
// K3gemm (R5 shape, proven): 32(i) x 128(n) tile, 4x4 microtile, 256 thr,
// grid (2,8,80) = 1280 blocks = 5/CU. Ascending-j -> bit-identical.
// ---------------------------------------------------------------------------
__global__ __launch_bounds__(256) void k3_bias_gemm(
    const uint32_t* __restrict__ vb, const float* __restrict__ bias_table,
    float* __restrict__ p0, float* __restrict__ p1,
    float* __restrict__ p2, float* __restrict__ p3)
{
    __shared__ float sbl[544];
    __shared__ float At[32][36];   // [j-in-chunk][i-local 0..31]
    __shared__ float Bt[32][132];  // [j-in-chunk][n-local 0..127]

    const int z = blockIdx.z;
    const int h = z / 10;
    const int p = z % 10;
    const int ti = TI_OF[p], tj = TJ_OF[p];
    const int dt = ti - tj;
    const int iT = blockIdx.y;           // 0..7 (32 rows each)
    const int nBase = blockIdx.x * 128;  // 0 or 128
    const int tid = threadIdx.x;

    // stage bias window
    const int base = 3363 + 961 * dt + 62 * iT - 480;
    for (int s = tid; s < 544; s += 256) {
        const int gidx = base + s;
        sbl[s] = (gidx >= 0 && gidx < BIAS_ROWS_) ? bias_table[(size_t)gidx * NH_ + h] : 0.0f;
    }

    const int ty2 = tid >> 4, tx16 = tid & 15;   // staging mapping

    const int il0 = ty2 * 2;
    const int sRowBase = 480 + 31 * (il0 >> 4) + (il0 & 15) - tx16;

    const int n8 = tx16 * 8;
    const int nS = nBase + n8;
    const int bS = nS >> 5, d0S = nS & 31;
    const uint32_t* vbw = vb + ((size_t)bS * NH_ + h) * TN_ + tj * 256 + ty2;

    const int tyc = tid >> 5, txc = tid & 31;
    const int nA = nBase + txc * 4;
    const int bA = nA >> 5, dA = nA & 31;

    float acc[4][4];
#pragma unroll
    for (int i = 0; i < 4; ++i)
#pragma unroll
        for (int j = 0; j < 4; ++j) acc[i][j] = 0.0f;

    __syncthreads();  // sbl ready

    for (int kc = 0; kc < 8; ++kc) {
#pragma unroll
        for (int r1 = 0; r1 < 2; ++r1) {
            const int s0 = sRowBase - 31 * (kc * 2 + r1);
            float2 av;
            av.x = sbl[s0];
            av.y = sbl[s0 + 1];
            At[tx16 + 16 * r1][il0] = av.x;
            At[tx16 + 16 * r1][il0 + 1] = av.y;
        }
#pragma unroll
        for (int r = 0; r < 2; ++r) {
            const uint32_t wd = vbw[kc * 32 + 16 * r];
            float4 b0, b1;
            b0.x = (float)((wd >> d0S) & 1u);
            b0.y = (float)((wd >> (d0S + 1)) & 1u);
            b0.z = (float)((wd >> (d0S + 2)) & 1u);
            b0.w = (float)((wd >> (d0S + 3)) & 1u);
            b1.x = (float)((wd >> (d0S + 4)) & 1u);
            b1.y = (float)((wd >> (d0S + 5)) & 1u);
            b1.z = (float)((wd >> (d0S + 6)) & 1u);
            b1.w = (float)((wd >> (d0S + 7)) & 1u);
            *(float4*)&Bt[ty2 + 16 * r][n8] = b0;
            *(float4*)&Bt[ty2 + 16 * r][n8 + 4] = b1;
        }
        __syncthreads();
#pragma unroll
        for (int cc = 0; cc < 32; ++cc) {
            float a[4], bb[4];
            *(float4*)&a[0] = *(const float4*)&At[cc][tyc * 4];
            *(float4*)&bb[0] = *(const float4*)&Bt[cc][txc * 4];  // 16B stride
#pragma unroll
            for (int i = 0; i < 4; ++i)
#pragma unroll
                for (int j = 0; j < 4; ++j) acc[i][j] += a[i] * bb[j];
        }
        __syncthreads();
    }

    float* plane = (tj == 0) ? p0 : (tj == 1) ? p1 : (tj == 2) ? p2 : p3;
    const int nrows = (4 - tj) * 256;
    const int cA = h * 32 + dA;
#pragma unroll
    for (int r = 0; r < 4; ++r) {
        const int rowL = dt * 256 + iT * 32 + tyc * 4 + r;
        float4 s0;
        s0.x = acc[r][0]; s0.y = acc[r][1]; s0.z = acc[r][2]; s0.w = acc[r][3];
        *(float4*)&plane[((size_t)bA * nrows + rowL) * 256 + cA] = s0;
    }
}

// ---------------------------------------------------------------------------
// K4 (v3): 4 n's per thread, Gf row cached in 32 VGPRs. Grid (64,8).
// Per-(l,c) FP order unchanged -> bit-identical.
// ---------------------------------------------------------------------------
__global__ __launch_bounds__(256) void k4_lif2(
    const uint32_t* __restrict__ qb, const float* __restrict__ Gf,
    const float* __restrict__ p0, const float* __restrict__ p1,
    const float* __restrict__ p2, const float* __restrict__ p3,
    uint32_t* __restrict__ s2c)
{
    const int c = threadIdx.x;
    const int n0 = blockIdx.x * 4;      // n = n0 .. n0+3
    const int b = blockIdx.y;
    const int lane = c & 63;
    const int h = c >> 5, d = c & 31;
    const int bh = b * NH_ + h;
    const uint32_t* qbh = qb + (size_t)bh * TN_;

    float memv[4] = {0.0f, 0.0f, 0.0f, 0.0f};
    float spk[4] = {0.0f, 0.0f, 0.0f, 0.0f};
    for (int t = 0; t < T_; ++t) {
        const float* g = Gf + (size_t)(bh * 4 + t) * 1024 + d;
        float gv[32];
#pragma unroll
        for (int d2 = 0; d2 < 32; ++d2) gv[d2] = g[d2 * 32];
#pragma unroll
        for (int j = 0; j < 4; ++j) {
            const int l = t * N_ + n0 + j;
            const uint32_t q = qbh[l];
            float v = 0.0f;
#pragma unroll
            for (int d2 = 0; d2 < 32; ++d2)
                v += ((q >> d2) & 1u) ? gv[d2] : 0.0f;
            v += p0[((size_t)b * 1024 + l) * 256 + c];
            if (t >= 1) v += p1[((size_t)b * 768 + (l - 256)) * 256 + c];
            if (t >= 2) v += p2[((size_t)b * 512 + (l - 512)) * 256 + c];
            if (t >= 3) v += p3[((size_t)b * 256 + (l - 768)) * 256 + c];
            const float m = (memv[j] - 0.5f * spk[j]) * 0.25f + 0.125f * v;
            memv[j] = m;
            const float s = quant1f(m);
            spk[j] = s;
            const uint64_t mask = __ballot(s != 0.0f);
            if (lane == 0)
                s2c[((size_t)b * TN_ + l) * 8 + (c >> 5)] = (uint32_t)mask;
            else if (lane == 32)
                s2c[((size_t)b * TN_ + l) * 8 + (c >> 5)] = (uint32_t)(mask >> 32);
        }
    }
}

// ---------------------------------------------------------------------------
// K5: fused proj GEMM + bias + BN + final LIF -> writes d_out directly.
// ---------------------------------------------------------------------------
__global__ __launch_bounds__(256) void k5_proj_lif(
    const uint32_t* __restrict__ s2c, const float* __restrict__ w,
    const float* __restrict__ bp,
    const float* __restrict__ gamma, const float* __restrict__ beta,
    const float* __restrict__ mean, const float* __restrict__ var,
    float* __restrict__ out)
{
    __shared__ float At[128][36];    // [k-local][row], 32 rows (+4 pad)
    __shared__ uint32_t Sw[128 * 9]; // [l'][8 words] padded to 9
    const int nBase = blockIdx.x * 32;
    const int oBase = blockIdx.y * 32;
    const int b = blockIdx.z;
    const int tid = threadIdx.x;
    const int tx = tid & 31;   // n = nBase + tx
    const int ty = tid >> 5;   // rows ty*4..+3

#pragma unroll
    for (int j = 0; j < 4; ++j) {
        const int fidx = tid * 4 + j;
        const int lp = fidx >> 3, wsel = fidx & 7;
        const int t = lp >> 5, nn = lp & 31;
        Sw[lp * 9 + wsel] = s2c[((size_t)b * TN_ + t * 256 + nBase + nn) * 8 + wsel];
    }

    const int a_row = tid >> 3, a_kq = (tid & 7) * 16;

    float acc[4][4];
#pragma unroll
    for (int r = 0; r < 4; ++r)
#pragma unroll
        for (int t = 0; t < 4; ++t) acc[r][t] = 0.0f;

    for (int half = 0; half < 2; ++half) {
        if (half) __syncthreads();
#pragma unroll
        for (int j = 0; j < 4; ++j) {
            const float4 v = *(const float4*)&w[(size_t)(oBase + a_row) * C_ + half * 128 + a_kq + 4 * j];
            At[a_kq + 4 * j][a_row] = v.x;
            At[a_kq + 4 * j + 1][a_row] = v.y;
            At[a_kq + 4 * j + 2][a_row] = v.z;
            At[a_kq + 4 * j + 3][a_row] = v.w;
        }
        __syncthreads();

        for (int ks = 0; ks < 4; ++ks) {
            uint32_t wr[4];
#pragma unroll
            for (int t = 0; t < 4; ++t)
                wr[t] = Sw[(t * 32 + tx) * 9 + half * 4 + ks];
#pragma unroll
            for (int u = 0; u < 32; ++u) {
                float a[4];
                *(float4*)&a[0] = *(const float4*)&At[ks * 32 + u][ty * 4];
                float bv[4];
#pragma unroll
                for (int t = 0; t < 4; ++t) bv[t] = (float)((wr[t] >> u) & 1u);
#pragma unroll
                for (int r = 0; r < 4; ++r)
#pragma unroll
                    for (int t = 0; t < 4; ++t) acc[r][t] += a[r] * bv[t];
            }
        }
    }

#pragma unroll
    for (int r = 0; r < 4; ++r) {
        const int o = oBase + ty * 4 + r;
        const float inv = 1.0f / sqrtf(var[o] + 1e-5f);
        const float g = gamma[o] * inv;
        const float mn = mean[o], bt = beta[o], bpo = bp[o];
        float memv = 0.0f, spk = 0.0f;
#pragma unroll
        for (int t = 0; t < 4; ++t) {
            const float val = ((acc[r][t] + bpo) - mn) * g + bt;
            const float m = (memv - 0.5f * spk) * 0.25f + val;
            memv = m;
            const float s = quant1f(m);
            spk = s;
            out[(((size_t)t * B_ + b) * C_ + o) * N_ + nBase + tx] = s;
        }
    }
}

// ---------------------------------------------------------------------------
extern "C" void kernel_launch(void* const* d_in, const int* in_sizes, int n_in,
                              void* d_out, int out_size, void* d_ws, size_t ws_size,
                              hipStream_t stream)
{
    const float* x          = (const float*)d_in[0];
    const float* w_qkv      = (const float*)d_in[1];
    const float* qkv_gamma  = (const float*)d_in[2];
    const float* qkv_beta   = (const float*)d_in[3];
    const float* qkv_mean   = (const float*)d_in[4];
    const float* qkv_var    = (const float*)d_in[5];
    const float* bias_table = (const float*)d_in[6];
    const float* w_proj     = (const float*)d_in[7];
    const float* b_proj     = (const float*)d_in[8];
    const float* proj_gamma = (const float*)d_in[9];
    const float* proj_beta  = (const float*)d_in[10];
    const float* proj_mean  = (const float*)d_in[11];
    const float* proj_var   = (const float*)d_in[12];
    float* out = (float*)d_out;

    // workspace layout (bytes).
    char* ws = (char*)d_ws;
    float*    part0  = (float*)(ws + 1048576);      //  8388608 B
    float*    part1  = (float*)(ws + 9437184);      //  6291456 B
    float*    part2  = (float*)(ws + 15728640);     //  4194304 B
    float*    part3  = (float*)(ws + 19922944);     //  2097152 B (end 22020096)
    float*    Gf     = (float*)(ws + 25165824);     //  1048576 B (end 26214400)
    uint32_t* s2c    = (uint32_t*)(ws + 33554432);  //   262144 B (packed spikes)
    uint32_t* qbits  = (uint32_t*)(ws + 50331648);  //   262144 B
    uint32_t* kbits  = (uint32_t*)(ws + 50593792);
    uint32_t* vbits  = (uint32_t*)(ws + 50855936);  // end 51118080

    k1_qkv_lif<<<dim3(16, 6, 8), 128, 0, stream>>>(
        x, w_qkv, qkv_gamma, qkv_beta, qkv_mean, qkv_var, qbits, kbits, vbits);

    k3_gram<<<dim3(64, 4), 256, 0, stream>>>(kbits, vbits, Gf);

    k3_bias_gemm<<<dim3(2, 8, 80), 256, 0, stream>>>(
        vbits, bias_table, part0, part1, part2, part3);

    k4_lif2<<<dim3(64, 8), 256, 0, stream>>>(
        qbits, Gf, part0, part1, part2, part3, s2c);

    k5_proj_lif<<<dim3(8, 8, 8), 256, 0, stream>>>(
        s2c, w_proj, b_proj, proj_gamma, proj_beta, proj_mean, proj_var, out);
}

// Round 13
// 203.112 us; speedup vs baseline: 1.1968x; 1.1968x over previous
//
#include <hip/hip_runtime.h>
#include <stdint.h>
#include <math.h>

// Problem constants
constexpr int T_ = 4;
constexpr int B_ = 8;
constexpr int C_ = 256;
constexpr int N_ = 256;          // H*W
constexpr int TN_ = 1024;        // T*N
constexpr int NH_ = 8;           // heads
constexpr int O3_ = 768;         // 3*C
constexpr int BIAS_ROWS_ = 6727; // 7*31*31

__device__ __constant__ int TI_OF[10] = {0,1,1,2,2,2,3,3,3,3};
__device__ __constant__ int TJ_OF[10] = {0,0,1,0,1,2,0,1,2,3};

__device__ __forceinline__ float quant1f(float m) {
    return rintf(fminf(fmaxf(m, 0.0f), 1.0f));
}

// ---------------------------------------------------------------------------
// K1 (v6, FROZEN): fused qkv GEMM + BN + LIF + bit-pack. 49.5us best.
// LDS-issue model: 2.36M ds_read_b128 x 12cyc / 256CU = 46us floor; measured
// 49.5 (93% of ceiling). All alternatives measured or modeled worse:
// 4x4=52 (more reads), 8x8/128thr=57&95 (occupancy), 8x4+dbuf=94 (spill),
// dbuf-unroll1=54.7 (addressing overhead). 64-out/thread microtiles need
// <=128thr blocks or <=1.5 blk/CU — both fatal. This is the wall.
// ---------------------------------------------------------------------------
__global__ __launch_bounds__(256) void k1_qkv_lif(
    const float* __restrict__ x, const float* __restrict__ w,
    const float* __restrict__ gamma, const float* __restrict__ beta,
    const float* __restrict__ mean, const float* __restrict__ var,
    uint32_t* __restrict__ qb, uint32_t* __restrict__ kb, uint32_t* __restrict__ vb)
{
    __shared__ float At[32][68];   // [k][m], m=64 (+4 pad)
    __shared__ float Bt[32][132];  // [k][col], col = n_loc*4 + t (128, +4 pad)
    const int b = blockIdx.z;
    const int oBase = blockIdx.y * 64;
    const int nBase = blockIdx.x * 32;
    const int tid = threadIdx.x;
    const float* xb = x + (size_t)b * C_ * TN_;

    const int tyc = tid >> 5;        // 0..7
    const int txc = tid & 31;        // 0..31 = n_loc

    const int a_row0 = tid >> 4;     // 0..15
    const int a_k2 = (tid & 15) * 2; // 0..30
    const int b_n = tid & 31;        // 0..31
    const int b_kk0 = tid >> 5;      // 0..7 (4 k-rows, stride 8)

    float acc[8][4];                 // [o-local][t]
#pragma unroll
    for (int i = 0; i < 8; ++i)
#pragma unroll
        for (int j = 0; j < 4; ++j) acc[i][j] = 0.0f;

    for (int kc = 0; kc < 8; ++kc) {
        const int k0 = kc * 32;
#pragma unroll
        for (int r = 0; r < 4; ++r) {
            const int row = a_row0 + 16 * r;
            const float2 v = *(const float2*)&w[(size_t)(oBase + row) * C_ + k0 + a_k2];
            At[a_k2][row] = v.x;
            At[a_k2 + 1][row] = v.y;
        }
#pragma unroll
        for (int r = 0; r < 4; ++r) {
            const int kk = b_kk0 + 8 * r;
            const float* src = &xb[(size_t)(k0 + kk) * TN_ + nBase + b_n];
            float4 v;
            v.x = src[0];     // t = 0
            v.y = src[256];   // t = 1
            v.z = src[512];   // t = 2
            v.w = src[768];   // t = 3
            *(float4*)&Bt[kk][b_n * 4] = v;
        }
        __syncthreads();
#pragma unroll
        for (int cc = 0; cc < 32; ++cc) {
            float a[8], bb[4];
            *(float4*)&a[0] = *(const float4*)&At[cc][tyc * 8];
            *(float4*)&a[4] = *(const float4*)&At[cc][tyc * 8 + 4];
            *(float4*)&bb[0] = *(const float4*)&Bt[cc][txc * 4];
#pragma unroll
            for (int i = 0; i < 8; ++i)
#pragma unroll
                for (int j = 0; j < 4; ++j) acc[i][j] += a[i] * bb[j];
        }
        __syncthreads();
    }

    // epilogue: BN + LIF over t + bit-pack (bit-identical)
    const int o0 = oBase + tyc * 8;
    const int which = o0 >> 8;          // 0=q 1=k 2=v (block-uniform)
    const int h = (o0 >> 5) & 7;
    const int dq = tyc & 3;             // byte-quarter within the 32-d word
    const int n = nBase + txc;
    uint8_t* dst = (uint8_t*)((which == 0) ? qb : (which == 1) ? kb : vb);

    uint32_t bits[4] = {0u, 0u, 0u, 0u};
#pragma unroll
    for (int i = 0; i < 8; ++i) {
        const int o = o0 + i;
        const float inv = 1.0f / sqrtf(var[o] + 1e-5f);
        const float g = gamma[o] * inv;
        const float mn = mean[o], bt = beta[o];
        float memv = 0.0f, spk = 0.0f;
#pragma unroll
        for (int t = 0; t < 4; ++t) {
            const float val = (acc[i][t] - mn) * g + bt;
            const float m = (memv - 0.5f * spk) * 0.25f + val;
            memv = m;
            const float s = quant1f(m);
            spk = s;
            bits[t] |= ((uint32_t)s) << i;
        }
    }
#pragma unroll
    for (int t = 0; t < 4; ++t)
        dst[4 * (((size_t)b * NH_ + h) * TN_ + t * N_ + n) + dq] = (uint8_t)bits[t];
}

// ---------------------------------------------------------------------------
// K3gram (v2): fused tgp + cum, quarter-split. Grid (64,4) = 256 blocks.
// Integer popcount math -> exact.
// ---------------------------------------------------------------------------
__global__ __launch_bounds__(256) void k3_gram(
    const uint32_t* __restrict__ kb, const uint32_t* __restrict__ vb,
    float* __restrict__ Gf)
{
    __shared__ uint64_t ks8[8][4];
    __shared__ uint64_t vs[32][4];
    const int bh = blockIdx.x;
    const int qd = blockIdx.y;          // d2-quarter 0..3
    const int tid = threadIdx.x;
    const int q = tid >> 6, lane = tid & 63;
    const int d = tid & 31;
    const int d2l = tid >> 5;           // 0..7 (local d2)

    int cum = 0;

    for (int t = 0; t < T_; ++t) {
        const int j = t * N_ + tid;
        const uint32_t kw = kb[(size_t)bh * TN_ + j];
        const uint32_t vw = vb[(size_t)bh * TN_ + j];
#pragma unroll
        for (int dd = 0; dd < 8; ++dd) {
            const uint64_t mk = __ballot((kw >> (8 * qd + dd)) & 1u);
            if (lane == 0) ks8[dd][q] = mk;
        }
#pragma unroll
        for (int dd = 0; dd < 32; ++dd) {
            const uint64_t mv = __ballot((vw >> dd) & 1u);
            if (lane == 0) vs[dd][q] = mv;
        }
        __syncthreads();
        int p = 0;
#pragma unroll
        for (int w = 0; w < 4; ++w) p += __popcll(ks8[d2l][w] & vs[d][w]);
        cum += p;
        Gf[(size_t)(bh * 4 + t) * 1024 + 256 * qd + tid] = (float)cum;
        __syncthreads();   // ks8/vs reused next t
    }
}

// ---------------------------------------------------------------------------
// K3gemm (R5 shape, proven): 32(i) x 128(n) tile, 4x4 microtile, 256 thr,
// grid (2,8,80) = 1280 blocks = 5/CU. Ascending-j -> bit-identical.
// LDS-issue model: 2.62M reads -> ~51us floor; measured ~47. At the wall.
// ---------------------------------------------------------------------------
__global__ __launch_bounds__(256) void k3_bias_gemm(
    const uint32_t* __restrict__ vb, const float* __restrict__ bias_table,
    float* __restrict__ p0, float* __restrict__ p1,
    float* __restrict__ p2, float* __restrict__ p3)
{
    __shared__ float sbl[544];
    __shared__ float At[32][36];   // [j-in-chunk][i-local 0..31]
    __shared__ float Bt[32][132];  // [j-in-chunk][n-local 0..127]

    const int z = blockIdx.z;
    const int h = z / 10;
    const int p = z % 10;
    const int ti = TI_OF[p], tj = TJ_OF[p];
    const int dt = ti - tj;
    const int iT = blockIdx.y;           // 0..7 (32 rows each)
    const int nBase = blockIdx.x * 128;  // 0 or 128
    const int tid = threadIdx.x;

    // stage bias window
    const int base = 3363 + 961 * dt + 62 * iT - 480;
    for (int s = tid; s < 544; s += 256) {
        const int gidx = base + s;
        sbl[s] = (gidx >= 0 && gidx < BIAS_ROWS_) ? bias_table[(size_t)gidx * NH_ + h] : 0.0f;
    }

    const int ty2 = tid >> 4, tx16 = tid & 15;   // staging mapping

    const int il0 = ty2 * 2;
    const int sRowBase = 480 + 31 * (il0 >> 4) + (il0 & 15) - tx16;

    const int n8 = tx16 * 8;
    const int nS = nBase + n8;
    const int bS = nS >> 5, d0S = nS & 31;
    const uint32_t* vbw = vb + ((size_t)bS * NH_ + h) * TN_ + tj * 256 + ty2;

    const int tyc = tid >> 5, txc = tid & 31;
    const int nA = nBase + txc * 4;
    const int bA = nA >> 5, dA = nA & 31;

    float acc[4][4];
#pragma unroll
    for (int i = 0; i < 4; ++i)
#pragma unroll
        for (int j = 0; j < 4; ++j) acc[i][j] = 0.0f;

    __syncthreads();  // sbl ready

    for (int kc = 0; kc < 8; ++kc) {
#pragma unroll
        for (int r1 = 0; r1 < 2; ++r1) {
            const int s0 = sRowBase - 31 * (kc * 2 + r1);
            float2 av;
            av.x = sbl[s0];
            av.y = sbl[s0 + 1];
            At[tx16 + 16 * r1][il0] = av.x;
            At[tx16 + 16 * r1][il0 + 1] = av.y;
        }
#pragma unroll
        for (int r = 0; r < 2; ++r) {
            const uint32_t wd = vbw[kc * 32 + 16 * r];
            float4 b0, b1;
            b0.x = (float)((wd >> d0S) & 1u);
            b0.y = (float)((wd >> (d0S + 1)) & 1u);
            b0.z = (float)((wd >> (d0S + 2)) & 1u);
            b0.w = (float)((wd >> (d0S + 3)) & 1u);
            b1.x = (float)((wd >> (d0S + 4)) & 1u);
            b1.y = (float)((wd >> (d0S + 5)) & 1u);
            b1.z = (float)((wd >> (d0S + 6)) & 1u);
            b1.w = (float)((wd >> (d0S + 7)) & 1u);
            *(float4*)&Bt[ty2 + 16 * r][n8] = b0;
            *(float4*)&Bt[ty2 + 16 * r][n8 + 4] = b1;
        }
        __syncthreads();
#pragma unroll
        for (int cc = 0; cc < 32; ++cc) {
            float a[4], bb[4];
            *(float4*)&a[0] = *(const float4*)&At[cc][tyc * 4];
            *(float4*)&bb[0] = *(const float4*)&Bt[cc][txc * 4];  // 16B stride
#pragma unroll
            for (int i = 0; i < 4; ++i)
#pragma unroll
                for (int j = 0; j < 4; ++j) acc[i][j] += a[i] * bb[j];
        }
        __syncthreads();
    }

    float* plane = (tj == 0) ? p0 : (tj == 1) ? p1 : (tj == 2) ? p2 : p3;
    const int nrows = (4 - tj) * 256;
    const int cA = h * 32 + dA;
#pragma unroll
    for (int r = 0; r < 4; ++r) {
        const int rowL = dt * 256 + iT * 32 + tyc * 4 + r;
        float4 s0;
        s0.x = acc[r][0]; s0.y = acc[r][1]; s0.z = acc[r][2]; s0.w = acc[r][3];
        *(float4*)&plane[((size_t)bA * nrows + rowL) * 256 + cA] = s0;
    }
}

// ---------------------------------------------------------------------------
// K4 (v3): 4 n's per thread, Gf row cached in 32 VGPRs. Grid (64,8).
// Per-(l,c) FP order unchanged -> bit-identical.
// ---------------------------------------------------------------------------
__global__ __launch_bounds__(256) void k4_lif2(
    const uint32_t* __restrict__ qb, const float* __restrict__ Gf,
    const float* __restrict__ p0, const float* __restrict__ p1,
    const float* __restrict__ p2, const float* __restrict__ p3,
    uint32_t* __restrict__ s2c)
{
    const int c = threadIdx.x;
    const int n0 = blockIdx.x * 4;      // n = n0 .. n0+3
    const int b = blockIdx.y;
    const int lane = c & 63;
    const int h = c >> 5, d = c & 31;
    const int bh = b * NH_ + h;
    const uint32_t* qbh = qb + (size_t)bh * TN_;

    float memv[4] = {0.0f, 0.0f, 0.0f, 0.0f};
    float spk[4] = {0.0f, 0.0f, 0.0f, 0.0f};
    for (int t = 0; t < T_; ++t) {
        const float* g = Gf + (size_t)(bh * 4 + t) * 1024 + d;
        float gv[32];
#pragma unroll
        for (int d2 = 0; d2 < 32; ++d2) gv[d2] = g[d2 * 32];
#pragma unroll
        for (int j = 0; j < 4; ++j) {
            const int l = t * N_ + n0 + j;
            const uint32_t q = qbh[l];
            float v = 0.0f;
#pragma unroll
            for (int d2 = 0; d2 < 32; ++d2)
                v += ((q >> d2) & 1u) ? gv[d2] : 0.0f;
            v += p0[((size_t)b * 1024 + l) * 256 + c];
            if (t >= 1) v += p1[((size_t)b * 768 + (l - 256)) * 256 + c];
            if (t >= 2) v += p2[((size_t)b * 512 + (l - 512)) * 256 + c];
            if (t >= 3) v += p3[((size_t)b * 256 + (l - 768)) * 256 + c];
            const float m = (memv[j] - 0.5f * spk[j]) * 0.25f + 0.125f * v;
            memv[j] = m;
            const float s = quant1f(m);
            spk[j] = s;
            const uint64_t mask = __ballot(s != 0.0f);
            if (lane == 0)
                s2c[((size_t)b * TN_ + l) * 8 + (c >> 5)] = (uint32_t)mask;
            else if (lane == 32)
                s2c[((size_t)b * TN_ + l) * 8 + (c >> 5)] = (uint32_t)(mask >> 32);
        }
    }
}

// ---------------------------------------------------------------------------
// K5: fused proj GEMM + bias + BN + final LIF -> writes d_out directly.
// ---------------------------------------------------------------------------
__global__ __launch_bounds__(256) void k5_proj_lif(
    const uint32_t* __restrict__ s2c, const float* __restrict__ w,
    const float* __restrict__ bp,
    const float* __restrict__ gamma, const float* __restrict__ beta,
    const float* __restrict__ mean, const float* __restrict__ var,
    float* __restrict__ out)
{
    __shared__ float At[128][36];    // [k-local][row], 32 rows (+4 pad)
    __shared__ uint32_t Sw[128 * 9]; // [l'][8 words] padded to 9
    const int nBase = blockIdx.x * 32;
    const int oBase = blockIdx.y * 32;
    const int b = blockIdx.z;
    const int tid = threadIdx.x;
    const int tx = tid & 31;   // n = nBase + tx
    const int ty = tid >> 5;   // rows ty*4..+3

#pragma unroll
    for (int j = 0; j < 4; ++j) {
        const int fidx = tid * 4 + j;
        const int lp = fidx >> 3, wsel = fidx & 7;
        const int t = lp >> 5, nn = lp & 31;
        Sw[lp * 9 + wsel] = s2c[((size_t)b * TN_ + t * 256 + nBase + nn) * 8 + wsel];
    }

    const int a_row = tid >> 3, a_kq = (tid & 7) * 16;

    float acc[4][4];
#pragma unroll
    for (int r = 0; r < 4; ++r)
#pragma unroll
        for (int t = 0; t < 4; ++t) acc[r][t] = 0.0f;

    for (int half = 0; half < 2; ++half) {
        if (half) __syncthreads();
#pragma unroll
        for (int j = 0; j < 4; ++j) {
            const float4 v = *(const float4*)&w[(size_t)(oBase + a_row) * C_ + half * 128 + a_kq + 4 * j];
            At[a_kq + 4 * j][a_row] = v.x;
            At[a_kq + 4 * j + 1][a_row] = v.y;
            At[a_kq + 4 * j + 2][a_row] = v.z;
            At[a_kq + 4 * j + 3][a_row] = v.w;
        }
        __syncthreads();

        for (int ks = 0; ks < 4; ++ks) {
            uint32_t wr[4];
#pragma unroll
            for (int t = 0; t < 4; ++t)
                wr[t] = Sw[(t * 32 + tx) * 9 + half * 4 + ks];
#pragma unroll
            for (int u = 0; u < 32; ++u) {
                float a[4];
                *(float4*)&a[0] = *(const float4*)&At[ks * 32 + u][ty * 4];
                float bv[4];
#pragma unroll
                for (int t = 0; t < 4; ++t) bv[t] = (float)((wr[t] >> u) & 1u);
#pragma unroll
                for (int r = 0; r < 4; ++r)
#pragma unroll
                    for (int t = 0; t < 4; ++t) acc[r][t] += a[r] * bv[t];
            }
        }
    }

#pragma unroll
    for (int r = 0; r < 4; ++r) {
        const int o = oBase + ty * 4 + r;
        const float inv = 1.0f / sqrtf(var[o] + 1e-5f);
        const float g = gamma[o] * inv;
        const float mn = mean[o], bt = beta[o], bpo = bp[o];
        float memv = 0.0f, spk = 0.0f;
#pragma unroll
        for (int t = 0; t < 4; ++t) {
            const float val = ((acc[r][t] + bpo) - mn) * g + bt;
            const float m = (memv - 0.5f * spk) * 0.25f + val;
            memv = m;
            const float s = quant1f(m);
            spk = s;
            out[(((size_t)t * B_ + b) * C_ + o) * N_ + nBase + tx] = s;
        }
    }
}

// ---------------------------------------------------------------------------
extern "C" void kernel_launch(void* const* d_in, const int* in_sizes, int n_in,
                              void* d_out, int out_size, void* d_ws, size_t ws_size,
                              hipStream_t stream)
{
    const float* x          = (const float*)d_in[0];
    const float* w_qkv      = (const float*)d_in[1];
    const float* qkv_gamma  = (const float*)d_in[2];
    const float* qkv_beta   = (const float*)d_in[3];
    const float* qkv_mean   = (const float*)d_in[4];
    const float* qkv_var    = (const float*)d_in[5];
    const float* bias_table = (const float*)d_in[6];
    const float* w_proj     = (const float*)d_in[7];
    const float* b_proj     = (const float*)d_in[8];
    const float* proj_gamma = (const float*)d_in[9];
    const float* proj_beta  = (const float*)d_in[10];
    const float* proj_mean  = (const float*)d_in[11];
    const float* proj_var   = (const float*)d_in[12];
    float* out = (float*)d_out;

    // workspace layout (bytes).
    char* ws = (char*)d_ws;
    float*    part0  = (float*)(ws + 1048576);      //  8388608 B
    float*    part1  = (float*)(ws + 9437184);      //  6291456 B
    float*    part2  = (float*)(ws + 15728640);     //  4194304 B
    float*    part3  = (float*)(ws + 19922944);     //  2097152 B (end 22020096)
    float*    Gf     = (float*)(ws + 25165824);     //  1048576 B (end 26214400)
    uint32_t* s2c    = (uint32_t*)(ws + 33554432);  //   262144 B (packed spikes)
    uint32_t* qbits  = (uint32_t*)(ws + 50331648);  //   262144 B
    uint32_t* kbits  = (uint32_t*)(ws + 50593792);
    uint32_t* vbits  = (uint32_t*)(ws + 50855936);  // end 51118080

    k1_qkv_lif<<<dim3(8, 12, 8), 256, 0, stream>>>(
        x, w_qkv, qkv_gamma, qkv_beta, qkv_mean, qkv_var, qbits, kbits, vbits);

    k3_gram<<<dim3(64, 4), 256, 0, stream>>>(kbits, vbits, Gf);

    k3_bias_gemm<<<dim3(2, 8, 80), 256, 0, stream>>>(
        vbits, bias_table, part0, part1, part2, part3);

    k4_lif2<<<dim3(64, 8), 256, 0, stream>>>(
        qbits, Gf, part0, part1, part2, part3, s2c);

    k5_proj_lif<<<dim3(8, 8, 8), 256, 0, stream>>>(
        s2c, w_proj, b_proj, proj_gamma, proj_beta, proj_mean, proj_var, out);
}